// Round 5
// baseline (83.091 us; speedup 1.0000x reference)
//
#include <hip/hip_runtime.h>
#include <hip/hip_bf16.h>
#include <hip/hip_fp16.h>
#include <cstdint>
#include <cstddef>

typedef __attribute__((ext_vector_type(8))) short short8;
typedef __attribute__((ext_vector_type(8))) unsigned short ushort8;
typedef __attribute__((ext_vector_type(4))) unsigned short u16x4;
typedef __attribute__((ext_vector_type(4))) float f32x4;

#define BM 128
#define BN 128
#define BK 64
#define NC 16   // candidate pool per row (need true top-11; approx-rank noise margin = 5)

__device__ __forceinline__ void gload_lds16(const void* g, void* l) {
  typedef const __attribute__((address_space(1))) void* gp_t;
  typedef __attribute__((address_space(3))) void* lp_t;
  __builtin_amdgcn_global_load_lds((gp_t)(unsigned long long)(uintptr_t)g,
                                   (lp_t)(unsigned int)(unsigned long long)(uintptr_t)l,
                                   16, 0, 0);
}

__device__ __forceinline__ unsigned short f2h_bits(float f) {
  __half h = __float2half(f);
  return *reinterpret_cast<unsigned short*>(&h);
}

// wave64 min-reduce via DPP (VALU pipe, no LDS): result broadcast as scalar
__device__ __forceinline__ unsigned dpp_min_u32_bcast(unsigned v) {
  v = min(v, (unsigned)__builtin_amdgcn_update_dpp(-1, (int)v, 0x111, 0xF, 0xF, false));
  v = min(v, (unsigned)__builtin_amdgcn_update_dpp(-1, (int)v, 0x112, 0xF, 0xF, false));
  v = min(v, (unsigned)__builtin_amdgcn_update_dpp(-1, (int)v, 0x114, 0xF, 0xF, false));
  v = min(v, (unsigned)__builtin_amdgcn_update_dpp(-1, (int)v, 0x118, 0xF, 0xF, false));
  v = min(v, (unsigned)__builtin_amdgcn_update_dpp(-1, (int)v, 0x142, 0xF, 0xF, false));
  v = min(v, (unsigned)__builtin_amdgcn_update_dpp(-1, (int)v, 0x143, 0xF, 0xF, false));
  return (unsigned)__builtin_amdgcn_readlane((int)v, 63);
}

// wave64 sum-reduce via DPP: result broadcast as scalar
__device__ __forceinline__ float dpp_sum_f32_bcast(float v) {
  int x;
  x = __float_as_int(v);
  v += __int_as_float(__builtin_amdgcn_update_dpp(0, x, 0x111, 0xF, 0xF, false));
  x = __float_as_int(v);
  v += __int_as_float(__builtin_amdgcn_update_dpp(0, x, 0x112, 0xF, 0xF, false));
  x = __float_as_int(v);
  v += __int_as_float(__builtin_amdgcn_update_dpp(0, x, 0x114, 0xF, 0xF, false));
  x = __float_as_int(v);
  v += __int_as_float(__builtin_amdgcn_update_dpp(0, x, 0x118, 0xF, 0xF, false));
  x = __float_as_int(v);
  v += __int_as_float(__builtin_amdgcn_update_dpp(0, x, 0x142, 0xF, 0xF, false));
  x = __float_as_int(v);
  v += __int_as_float(__builtin_amdgcn_update_dpp(0, x, 0x143, 0xF, 0xF, false));
  return __int_as_float(__builtin_amdgcn_readlane(__float_as_int(v), 63));
}

// ---------- kernel 1: bf16 cast of feats + fp32 row squared-norms ----------
__global__ __launch_bounds__(256)
void prep_kernel(const float* __restrict__ zi, const float* __restrict__ zj,
                 unsigned short* __restrict__ fb, float* __restrict__ sq,
                 int n, int d) {
  __shared__ float wred[4];
  const int row = blockIdx.x;
  const int t = threadIdx.x, lane = t & 63, wave = t >> 6;
  const float* src = (row < n) ? (zi + (size_t)row * d) : (zj + (size_t)(row - n) * d);
  float s = 0.f;
  for (int c = t; c < d; c += 256) {
    float v = src[c];
    s += v * v;
    __hip_bfloat16 h = __float2bfloat16(v);
    fb[(size_t)row * d + c] = *reinterpret_cast<const unsigned short*>(&h);
  }
#pragma unroll
  for (int o = 32; o; o >>= 1) s += __shfl_xor(s, o, 64);
  if (lane == 0) wred[wave] = s;
  __syncthreads();
  if (t == 0) sq[row] = ((wred[0] + wred[1]) + wred[2]) + wred[3];
}

// ---------- kernel 2: symmetric bf16 MFMA GEMM -> approx d^2 (fp16, diag=+inf) ----------
// Computes only upper-triangular tiles; mirror tile written via LDS fp16 transpose.
__global__ __launch_bounds__(256)
void gemm_pd_kernel(const unsigned short* __restrict__ fb,
                    const float* __restrict__ sq,
                    __half* __restrict__ pdh, int b, int d) {
  if (blockIdx.y * BM > blockIdx.x * BN) return;   // lower-tri tiles: mirrored instead

  __shared__ char smem[32768];
  unsigned short* smA = (unsigned short*)smem;            // 16 KB (K-loop)
  unsigned short* smB = (unsigned short*)(smem + 16384);  // 16 KB (K-loop)
  char* tileT = smem;                                     // 32 KB (epilogue reuse)

  const int t = threadIdx.x;
  const int lane = t & 63;
  const int wave = t >> 6;
  const int wr = wave >> 1, wc = wave & 1;
  const int rowBase = blockIdx.y * BM;
  const int colBase = blockIdx.x * BN;
  const int l15 = lane & 15, l4 = lane >> 4;

  f32x4 acc[4][4] = {};

  for (int kt = 0; kt < d; kt += BK) {
#pragma unroll
    for (int it = 0; it < 4; ++it) {
      const int c = it * 256 + t;      // 1024 16B-chunks per 128x64 tile
      const int r = c >> 3;
      const int kk = (c & 7) * 8;
      gload_lds16(fb + (size_t)(rowBase + r) * d + kt + kk, (char*)smA + c * 16);
      gload_lds16(fb + (size_t)(colBase + r) * d + kt + kk, (char*)smB + c * 16);
    }
    __syncthreads();
#pragma unroll
    for (int ks = 0; ks < 2; ++ks) {
      short8 af[4], bfr[4];
#pragma unroll
      for (int m = 0; m < 4; ++m)
        af[m] = *(const short8*)&smA[(wr * 64 + m * 16 + l15) * BK + ks * 32 + l4 * 8];
#pragma unroll
      for (int nn = 0; nn < 4; ++nn)
        bfr[nn] = *(const short8*)&smB[(wc * 64 + nn * 16 + l15) * BK + ks * 32 + l4 * 8];
#pragma unroll
      for (int m = 0; m < 4; ++m)
#pragma unroll
        for (int nn = 0; nn < 4; ++nn)
          acc[m][nn] = __builtin_amdgcn_mfma_f32_16x16x32_bf16(af[m], bfr[nn], acc[m][nn], 0, 0, 0);
    }
    __syncthreads();
  }

  const bool offdiag = (rowBase != colBase);
#pragma unroll
  for (int m = 0; m < 4; ++m) {
    const int r0 = wr * 64 + m * 16 + l4 * 4;        // local row base (4 rows)
#pragma unroll
    for (int nn = 0; nn < 4; ++nn) {
      const int cl = wc * 64 + nn * 16 + l15;        // local col
      const int gc = colBase + cl;
      const float sqc = sq[gc];
      u16x4 hv;
#pragma unroll
      for (int rg = 0; rg < 4; ++rg) {
        const int gr = rowBase + r0 + rg;
        float d2 = fmaxf(sq[gr] + sqc - 2.0f * acc[m][nn][rg], 0.0f);
        unsigned short bits = (gr == gc) ? (unsigned short)0x7C00 : f2h_bits(d2);
        hv[rg] = bits;
        *(unsigned short*)((char*)pdh + ((size_t)gr * b + gc) * 2) = bits;
      }
      if (offdiag)   // stash transposed (XOR-swizzled to spread banks)
        *(u16x4*)(tileT + cl * 256 + ((r0 * 2) ^ ((cl & 7) << 4))) = hv;
    }
  }

  if (offdiag) {     // block-uniform branch
    __syncthreads();
#pragma unroll
    for (int it = 0; it < 16; ++it) {
      const int tc = it * 8 + (t >> 5);              // transposed row (orig col)
      const int rc = (t & 31) * 4;                   // 4 fp16 = 8 B
      u16x4 v = *(const u16x4*)(tileT + tc * 256 + ((rc * 2) ^ ((tc & 7) << 4)));
      *(u16x4*)((char*)pdh + (((size_t)(colBase + tc)) * b + rowBase + rc) * 2) = v;
    }
  }
}

// ---------- kernel 3: wave-per-row top-16 select (DPP-only), exact re-rank, loss ----------
// Requires b == 4096 (8 chunks x 64 lanes x 8), d == 512, C == 128.
__global__ __launch_bounds__(256)
void topk_loss_kernel(const __half* __restrict__ pdh,
                      const float* __restrict__ zi, const float* __restrict__ zj,
                      const float* __restrict__ pi, const float* __restrict__ pj,
                      const int* __restrict__ labels,
                      const float* __restrict__ sq,
                      float* __restrict__ rowsum,
                      int n, int d, int C, int b) {
  const int t = threadIdx.x, lane = t & 63, wave = t >> 6;
  const int row = blockIdx.x * 4 + wave;

  // ---- Phase A: raw fp16 chunks in VGPRs; top-16 via DPP wave argmin rounds ----
  const ushort8* rowp = (const ushort8*)(pdh + (size_t)row * b);
  ushort8 h[8];
#pragma unroll
  for (int ch = 0; ch < 8; ++ch) h[ch] = rowp[ch * 64 + lane];

  unsigned cmin[8];
#pragma unroll
  for (int ch = 0; ch < 8; ++ch) {
    unsigned mn = 0xFFFFFFFFu;
#pragma unroll
    for (int j = 0; j < 8; ++j) {
      unsigned pk = ((unsigned)h[ch][j] << 16) | (unsigned)(ch * 512 + lane * 8 + j);
      mn = min(mn, pk);
    }
    cmin[ch] = mn;
  }

  int c[NC];
#pragma unroll
  for (int r = 0; r < NC; ++r) {
    unsigned m0 = min(min(cmin[0], cmin[1]), min(cmin[2], cmin[3]));
    unsigned m1 = min(min(cmin[4], cmin[5]), min(cmin[6], cmin[7]));
    const unsigned g = dpp_min_u32_bcast(min(m0, m1));
    const int idx = (int)(g & 0xFFFFu);
    c[r] = idx;
    if (((idx >> 3) & 63) == lane) {   // owner invalidates + rebuilds its chunk-min
      const int ch = idx >> 9, jj = idx & 7;
#pragma unroll
      for (int cc = 0; cc < 8; ++cc)
        if (cc == ch) {
          unsigned mn = 0xFFFFFFFFu;
#pragma unroll
          for (int j = 0; j < 8; ++j) {
            if (j == jj) h[cc][j] = (unsigned short)0xFFFFu;
            unsigned pk = ((unsigned)h[cc][j] << 16) | (unsigned)(cc * 512 + lane * 8 + j);
            mn = min(mn, pk);
          }
          cmin[cc] = mn;
        }
    }
  }

  // ---- Phase B: exact fp32 d2 for the 16 candidates (my row in 8 VGPRs) ----
  const float* fme = (row < n) ? (zi + (size_t)row * d) : (zj + (size_t)(row - n) * d);
  float fr[8];
#pragma unroll
  for (int q = 0; q < 8; ++q) fr[q] = fme[lane + 64 * q];
  const float sqr = sq[row];

  float p[NC];
#pragma unroll
  for (int k = 0; k < NC; ++k) {
    const int j = c[k];
    const float* g = (j < n) ? (zi + (size_t)j * d) : (zj + (size_t)(j - n) * d);
    float part = 0.f;
#pragma unroll
    for (int q = 0; q < 8; ++q) part += fr[q] * g[lane + 64 * q];
    const float dot = dpp_sum_f32_bcast(part);
    const float d2 = sqr + sq[j] - 2.0f * dot;
    p[k] = sqrtf(fmaxf(d2, 0.0f));
  }

  // ---- Phase C: radius + branchless pairwise ranks (compile-time indices) ----
  float r0 = p[0];
#pragma unroll
  for (int k = 1; k < NC; ++k) r0 = fminf(r0, p[k]);

  int rank[NC];
#pragma unroll
  for (int k = 0; k < NC; ++k) rank[k] = 0;
#pragma unroll
  for (int k = 1; k < NC; ++k) {
#pragma unroll
    for (int j = 0; j < k; ++j) {
      const bool tt = p[j] <= p[k];   // tie -> earlier extraction wins
      rank[k] += tt ? 1 : 0;
      rank[j] += tt ? 0 : 1;
    }
  }

  // ---- Phase D: masked contributions; prob dot only when mask passes ----
  const int ri = (row < n) ? row : row - n;
  const int li = labels[ri];
  const float* pme = (row < n) ? (pi + (size_t)row * C) : (pj + (size_t)(row - n) * C);
  const float pr0 = pme[lane], pr1 = pme[lane + 64];

  float tot = 0.f;
#pragma unroll
  for (int k = 0; k < NC; ++k) {
    const int j = c[k];
    const int rj = (j < n) ? j : j - n;
    const int lj = labels[rj];
    const bool m = (rank[k] < 10) & (li != -1) & (lj != -1) & (li == lj) & (ri != rj);
    if (m) {   // identical across lanes -> uniform branch
      const float* q = (j < n) ? (pi + (size_t)j * C) : (pj + (size_t)(j - n) * C);
      float part = pr0 * q[lane] + pr1 * q[lane + 64];
      const float inner = dpp_sum_f32_bcast(part);
      const float w = 1.0f - fminf(fmaxf((p[k] - r0) / r0, 0.0f), 1.0f);
      tot += w * inner;
    }
  }
  if (lane == 0) rowsum[row] = tot;
}

// ---------- kernel 4: deterministic final reduce ----------
__global__ __launch_bounds__(256)
void final_reduce_kernel(const float* __restrict__ rowsum, float* __restrict__ out, int b) {
  __shared__ float wredf[4];
  const int t = threadIdx.x, lane = t & 63, wave = t >> 6;
  float s = 0.f;
  for (int c = t; c < b; c += 256) s += rowsum[c];
#pragma unroll
  for (int o = 32; o; o >>= 1) s += __shfl_xor(s, o, 64);
  if (lane == 0) wredf[wave] = s;
  __syncthreads();
  if (t == 0) {
    float tot = ((wredf[0] + wredf[1]) + wredf[2]) + wredf[3];
    out[0] = tot / ((float)b * (float)b);
  }
}

extern "C" void kernel_launch(void* const* d_in, const int* in_sizes, int n_in,
                              void* d_out, int out_size, void* d_ws, size_t ws_size,
                              hipStream_t stream) {
  const float* zi = (const float*)d_in[0];
  const float* zj = (const float*)d_in[1];
  const float* pi = (const float*)d_in[2];
  const float* pj = (const float*)d_in[3];
  const int* labels = (const int*)d_in[4];

  const int n = in_sizes[4];          // 2048
  const int d = in_sizes[0] / n;      // 512
  const int C = in_sizes[2] / n;      // 128
  const int b = 2 * n;                // 4096

  char* ws = (char*)d_ws;
  size_t off = 0;
  unsigned short* fb = (unsigned short*)(ws + off);
  off += ((size_t)b * d * 2 + 255) & ~(size_t)255;
  float* sq = (float*)(ws + off);
  off += ((size_t)b * 4 + 255) & ~(size_t)255;
  float* rowsum = (float*)(ws + off);
  off += ((size_t)b * 4 + 255) & ~(size_t)255;
  __half* pdh = (__half*)(ws + off);
  off += (size_t)b * b * 2;
  if (ws_size < off) return;  // workspace too small — bail rather than corrupt

  prep_kernel<<<b, 256, 0, stream>>>(zi, zj, fb, sq, n, d);
  dim3 grid(b / BN, b / BM);
  gemm_pd_kernel<<<grid, 256, 0, stream>>>(fb, sq, pdh, b, d);
  topk_loss_kernel<<<b / 4, 256, 0, stream>>>(pdh, zi, zj, pi, pj, labels, sq, rowsum, n, d, C, b);
  final_reduce_kernel<<<1, 256, 0, stream>>>(rowsum, (float*)d_out, b);
}

// Round 6
// 75.259 us; speedup vs baseline: 1.1041x; 1.1041x over previous
//
#include <hip/hip_runtime.h>
#include <hip/hip_bf16.h>
#include <hip/hip_fp16.h>
#include <cstdint>
#include <cstddef>

typedef __attribute__((ext_vector_type(8))) short short8;
typedef __attribute__((ext_vector_type(8))) unsigned short ushort8;
typedef __attribute__((ext_vector_type(4))) unsigned short u16x4;
typedef __attribute__((ext_vector_type(4))) float f32x4;

#define BM 128
#define BN 128
#define BK 64
#define NC 16   // candidate pool per row (need true top-11; approx-rank noise margin = 5)

__device__ __forceinline__ void gload_lds16(const void* g, void* l) {
  typedef const __attribute__((address_space(1))) void* gp_t;
  typedef __attribute__((address_space(3))) void* lp_t;
  __builtin_amdgcn_global_load_lds((gp_t)(unsigned long long)(uintptr_t)g,
                                   (lp_t)(unsigned int)(unsigned long long)(uintptr_t)l,
                                   16, 0, 0);
}

__device__ __forceinline__ unsigned short f2h_bits(float f) {
  __half h = __float2half(f);
  return *reinterpret_cast<unsigned short*>(&h);
}

// ---------- kernel 1: bf16 cast of feats + fp32 row squared-norms ----------
__global__ __launch_bounds__(256)
void prep_kernel(const float* __restrict__ zi, const float* __restrict__ zj,
                 unsigned short* __restrict__ fb, float* __restrict__ sq,
                 int n, int d) {
  __shared__ float wred[4];
  const int row = blockIdx.x;
  const int t = threadIdx.x, lane = t & 63, wave = t >> 6;
  const float* src = (row < n) ? (zi + (size_t)row * d) : (zj + (size_t)(row - n) * d);
  float s = 0.f;
  for (int c = t; c < d; c += 256) {
    float v = src[c];
    s += v * v;
    __hip_bfloat16 h = __float2bfloat16(v);
    fb[(size_t)row * d + c] = *reinterpret_cast<const unsigned short*>(&h);
  }
#pragma unroll
  for (int o = 32; o; o >>= 1) s += __shfl_xor(s, o, 64);
  if (lane == 0) wred[wave] = s;
  __syncthreads();
  if (t == 0) sq[row] = ((wred[0] + wred[1]) + wred[2]) + wred[3];
}

// ---------- kernel 2: symmetric bf16 MFMA GEMM -> approx d^2 (fp16, diag=+inf) ----------
// Computes only upper-triangular tiles; mirror tile written via LDS fp16 transpose.
__global__ __launch_bounds__(256)
void gemm_pd_kernel(const unsigned short* __restrict__ fb,
                    const float* __restrict__ sq,
                    __half* __restrict__ pdh, int b, int d) {
  if (blockIdx.y * BM > blockIdx.x * BN) return;   // lower-tri tiles: mirrored instead

  __shared__ char smem[32768];
  unsigned short* smA = (unsigned short*)smem;            // 16 KB (K-loop)
  unsigned short* smB = (unsigned short*)(smem + 16384);  // 16 KB (K-loop)
  char* tileT = smem;                                     // 32 KB (epilogue reuse)

  const int t = threadIdx.x;
  const int lane = t & 63;
  const int wave = t >> 6;
  const int wr = wave >> 1, wc = wave & 1;
  const int rowBase = blockIdx.y * BM;
  const int colBase = blockIdx.x * BN;
  const int l15 = lane & 15, l4 = lane >> 4;

  f32x4 acc[4][4] = {};

  for (int kt = 0; kt < d; kt += BK) {
#pragma unroll
    for (int it = 0; it < 4; ++it) {
      const int c = it * 256 + t;      // 1024 16B-chunks per 128x64 tile
      const int r = c >> 3;
      const int kk = (c & 7) * 8;
      gload_lds16(fb + (size_t)(rowBase + r) * d + kt + kk, (char*)smA + c * 16);
      gload_lds16(fb + (size_t)(colBase + r) * d + kt + kk, (char*)smB + c * 16);
    }
    __syncthreads();
#pragma unroll
    for (int ks = 0; ks < 2; ++ks) {
      short8 af[4], bfr[4];
#pragma unroll
      for (int m = 0; m < 4; ++m)
        af[m] = *(const short8*)&smA[(wr * 64 + m * 16 + l15) * BK + ks * 32 + l4 * 8];
#pragma unroll
      for (int nn = 0; nn < 4; ++nn)
        bfr[nn] = *(const short8*)&smB[(wc * 64 + nn * 16 + l15) * BK + ks * 32 + l4 * 8];
#pragma unroll
      for (int m = 0; m < 4; ++m)
#pragma unroll
        for (int nn = 0; nn < 4; ++nn)
          acc[m][nn] = __builtin_amdgcn_mfma_f32_16x16x32_bf16(af[m], bfr[nn], acc[m][nn], 0, 0, 0);
    }
    __syncthreads();
  }

  const bool offdiag = (rowBase != colBase);
#pragma unroll
  for (int m = 0; m < 4; ++m) {
    const int r0 = wr * 64 + m * 16 + l4 * 4;        // local row base (4 rows)
#pragma unroll
    for (int nn = 0; nn < 4; ++nn) {
      const int cl = wc * 64 + nn * 16 + l15;        // local col
      const int gc = colBase + cl;
      const float sqc = sq[gc];
      u16x4 hv;
#pragma unroll
      for (int rg = 0; rg < 4; ++rg) {
        const int gr = rowBase + r0 + rg;
        float d2 = fmaxf(sq[gr] + sqc - 2.0f * acc[m][nn][rg], 0.0f);
        unsigned short bits = (gr == gc) ? (unsigned short)0x7C00 : f2h_bits(d2);
        hv[rg] = bits;
        *(unsigned short*)((char*)pdh + ((size_t)gr * b + gc) * 2) = bits;
      }
      if (offdiag)   // stash transposed (XOR-swizzled to spread banks)
        *(u16x4*)(tileT + cl * 256 + ((r0 * 2) ^ ((cl & 7) << 4))) = hv;
    }
  }

  if (offdiag) {     // block-uniform branch
    __syncthreads();
#pragma unroll
    for (int it = 0; it < 16; ++it) {
      const int tc = it * 8 + (t >> 5);              // transposed row (orig col)
      const int rc = (t & 31) * 4;                   // 4 fp16 = 8 B
      u16x4 v = *(const u16x4*)(tileT + tc * 256 + ((rc * 2) ^ ((tc & 7) << 4)));
      *(u16x4*)((char*)pdh + (((size_t)(colBase + tc)) * b + rowBase + rc) * 2) = v;
    }
  }
}

// ---------- kernel 3: wave-per-row top-16 select (shuffle-only), exact re-rank, loss ----------
// Requires b == 4096 (64 chunks of 64 lanes), d == 512, C == 128.
__global__ __launch_bounds__(256)
void topk_loss_kernel(const __half* __restrict__ pdh,
                      const float* __restrict__ zi, const float* __restrict__ zj,
                      const float* __restrict__ pi, const float* __restrict__ pj,
                      const int* __restrict__ labels,
                      const float* __restrict__ sq,
                      float* __restrict__ rowsum,
                      int n, int d, int C, int b) {
  const int t = threadIdx.x, lane = t & 63, wave = t >> 6;
  const int row = blockIdx.x * 4 + wave;

  // ---- Phase A: load row of packed (fp16 d2, idx); top-16 by repeated wave argmin ----
  const ushort8* rowp = (const ushort8*)(pdh + (size_t)row * b);
  unsigned vv[8][8];
  unsigned cmin[8];
#pragma unroll
  for (int ch = 0; ch < 8; ++ch) {
    ushort8 h = rowp[ch * 64 + lane];
    unsigned mn = 0xFFFFFFFFu;
#pragma unroll
    for (int j = 0; j < 8; ++j) {
      unsigned pk = ((unsigned)h[j] << 16) | (unsigned)(ch * 512 + lane * 8 + j);
      vv[ch][j] = pk;
      mn = min(mn, pk);
    }
    cmin[ch] = mn;
  }

  int c[NC];
#pragma unroll
  for (int r = 0; r < NC; ++r) {
    unsigned best = cmin[0];
#pragma unroll
    for (int ch = 1; ch < 8; ++ch) best = min(best, cmin[ch]);
#pragma unroll
    for (int o = 32; o; o >>= 1) {
      unsigned q = __shfl_xor(best, o, 64);
      best = min(best, q);
    }
    const int idx = (int)(best & 0xFFFFu);
    c[r] = idx;
    if (((idx >> 3) & 63) == lane) {       // owner invalidates + rebuilds its chunk-min
      const int ch = idx >> 9, jj = idx & 7;
#pragma unroll
      for (int cc = 0; cc < 8; ++cc) {
        if (cc == ch) {
          unsigned mn = 0xFFFFFFFFu;
#pragma unroll
          for (int j = 0; j < 8; ++j) {
            if (j == jj) vv[cc][j] = 0xFFFFFFFFu;
            mn = min(mn, vv[cc][j]);
          }
          cmin[cc] = mn;
        }
      }
    }
  }

  // ---- Phase B: exact fp32 d2 for the 16 candidates (my row in 8 VGPRs) ----
  const float* fme = (row < n) ? (zi + (size_t)row * d) : (zj + (size_t)(row - n) * d);
  float fr[8];
#pragma unroll
  for (int q = 0; q < 8; ++q) fr[q] = fme[lane + 64 * q];
  const float sqr = sq[row];

  float p[NC];
#pragma unroll
  for (int k = 0; k < NC; ++k) {
    const int j = c[k];
    const float* g = (j < n) ? (zi + (size_t)j * d) : (zj + (size_t)(j - n) * d);
    float part = 0.f;
#pragma unroll
    for (int q = 0; q < 8; ++q) part += fr[q] * g[lane + 64 * q];
#pragma unroll
    for (int o = 32; o; o >>= 1) part += __shfl_xor(part, o, 64);
    const float d2 = sqr + sq[j] - 2.0f * part;
    p[k] = sqrtf(fmaxf(d2, 0.0f));
  }

  // ---- Phase C: radius + branchless pairwise ranks (all compile-time indices) ----
  float r0 = p[0];
#pragma unroll
  for (int k = 1; k < NC; ++k) r0 = fminf(r0, p[k]);

  int rank[NC];
#pragma unroll
  for (int k = 0; k < NC; ++k) rank[k] = 0;
#pragma unroll
  for (int k = 1; k < NC; ++k) {
#pragma unroll
    for (int j = 0; j < k; ++j) {
      const bool tt = p[j] <= p[k];   // tie -> earlier extraction wins (lower approx (d2,idx))
      rank[k] += tt ? 1 : 0;
      rank[j] += tt ? 0 : 1;
    }
  }

  // ---- Phase D: masked contributions; prob dot only when mask passes (wave-uniform) ----
  const int ri = (row < n) ? row : row - n;
  const int li = labels[ri];
  const float* pme = (row < n) ? (pi + (size_t)row * C) : (pj + (size_t)(row - n) * C);
  const float pr0 = pme[lane], pr1 = pme[lane + 64];

  float tot = 0.f;
#pragma unroll
  for (int k = 0; k < NC; ++k) {
    const int j = c[k];
    const int rj = (j < n) ? j : j - n;
    const int lj = labels[rj];
    const bool m = (rank[k] < 10) & (li != -1) & (lj != -1) & (li == lj) & (ri != rj);
    if (m) {   // identical across lanes -> uniform branch
      const float* q = (j < n) ? (pi + (size_t)j * C) : (pj + (size_t)(j - n) * C);
      float part = pr0 * q[lane] + pr1 * q[lane + 64];
#pragma unroll
      for (int o = 32; o; o >>= 1) part += __shfl_xor(part, o, 64);
      const float w = 1.0f - fminf(fmaxf((p[k] - r0) / r0, 0.0f), 1.0f);
      tot += w * part;
    }
  }
  if (lane == 0) rowsum[row] = tot;
}

// ---------- kernel 4: deterministic final reduce ----------
__global__ __launch_bounds__(256)
void final_reduce_kernel(const float* __restrict__ rowsum, float* __restrict__ out, int b) {
  __shared__ float wredf[4];
  const int t = threadIdx.x, lane = t & 63, wave = t >> 6;
  float s = 0.f;
  for (int c = t; c < b; c += 256) s += rowsum[c];
#pragma unroll
  for (int o = 32; o; o >>= 1) s += __shfl_xor(s, o, 64);
  if (lane == 0) wredf[wave] = s;
  __syncthreads();
  if (t == 0) {
    float tot = ((wredf[0] + wredf[1]) + wredf[2]) + wredf[3];
    out[0] = tot / ((float)b * (float)b);
  }
}

extern "C" void kernel_launch(void* const* d_in, const int* in_sizes, int n_in,
                              void* d_out, int out_size, void* d_ws, size_t ws_size,
                              hipStream_t stream) {
  const float* zi = (const float*)d_in[0];
  const float* zj = (const float*)d_in[1];
  const float* pi = (const float*)d_in[2];
  const float* pj = (const float*)d_in[3];
  const int* labels = (const int*)d_in[4];

  const int n = in_sizes[4];          // 2048
  const int d = in_sizes[0] / n;      // 512
  const int C = in_sizes[2] / n;      // 128
  const int b = 2 * n;                // 4096

  char* ws = (char*)d_ws;
  size_t off = 0;
  unsigned short* fb = (unsigned short*)(ws + off);
  off += ((size_t)b * d * 2 + 255) & ~(size_t)255;
  float* sq = (float*)(ws + off);
  off += ((size_t)b * 4 + 255) & ~(size_t)255;
  float* rowsum = (float*)(ws + off);
  off += ((size_t)b * 4 + 255) & ~(size_t)255;
  __half* pdh = (__half*)(ws + off);
  off += (size_t)b * b * 2;
  if (ws_size < off) return;  // workspace too small — bail rather than corrupt

  prep_kernel<<<b, 256, 0, stream>>>(zi, zj, fb, sq, n, d);
  dim3 grid(b / BN, b / BM);
  gemm_pd_kernel<<<grid, 256, 0, stream>>>(fb, sq, pdh, b, d);
  topk_loss_kernel<<<b / 4, 256, 0, stream>>>(pdh, zi, zj, pi, pj, labels, sq, rowsum, n, d, C, b);
  final_reduce_kernel<<<1, 256, 0, stream>>>(rowsum, (float*)d_out, b);
}

// Round 7
// 74.123 us; speedup vs baseline: 1.1210x; 1.0153x over previous
//
#include <hip/hip_runtime.h>
#include <hip/hip_bf16.h>
#include <hip/hip_fp16.h>
#include <cstdint>
#include <cstddef>

typedef __attribute__((ext_vector_type(8))) short short8;
typedef __attribute__((ext_vector_type(8))) unsigned short ushort8;
typedef __attribute__((ext_vector_type(4))) unsigned short u16x4;
typedef __attribute__((ext_vector_type(4))) float f32x4;

#define BM 128
#define BN 128
#define BK 64
#define NC 16   // candidate pool per row (need true top-11; approx-rank noise margin = 5)

__device__ __forceinline__ void gload_lds16(const void* g, void* l) {
  typedef const __attribute__((address_space(1))) void* gp_t;
  typedef __attribute__((address_space(3))) void* lp_t;
  __builtin_amdgcn_global_load_lds((gp_t)(unsigned long long)(uintptr_t)g,
                                   (lp_t)(unsigned int)(unsigned long long)(uintptr_t)l,
                                   16, 0, 0);
}

__device__ __forceinline__ unsigned short f2h_bits(float f) {
  __half h = __float2half(f);
  return *reinterpret_cast<unsigned short*>(&h);
}

// ---------- kernel 1: bf16 cast of feats + fp32 row squared-norms ----------
__global__ __launch_bounds__(256)
void prep_kernel(const float* __restrict__ zi, const float* __restrict__ zj,
                 unsigned short* __restrict__ fb, float* __restrict__ sq,
                 int n, int d) {
  __shared__ float wred[4];
  const int row = blockIdx.x;
  const int t = threadIdx.x, lane = t & 63, wave = t >> 6;
  const float* src = (row < n) ? (zi + (size_t)row * d) : (zj + (size_t)(row - n) * d);
  float s = 0.f;
  for (int c = t; c < d; c += 256) {
    float v = src[c];
    s += v * v;
    __hip_bfloat16 h = __float2bfloat16(v);
    fb[(size_t)row * d + c] = *reinterpret_cast<const unsigned short*>(&h);
  }
#pragma unroll
  for (int o = 32; o; o >>= 1) s += __shfl_xor(s, o, 64);
  if (lane == 0) wred[wave] = s;
  __syncthreads();
  if (t == 0) sq[row] = ((wred[0] + wred[1]) + wred[2]) + wred[3];
}

// ---------- kernel 2: bf16 MFMA GEMM -> approx d^2 (fp16, diag=+inf) ----------
// Epilogue stores the C-fragment quad TRANSPOSED (d^2 is symmetric), turning
// 4 scalar 2B stores into one u16x4 store (32B segments, 4x fewer instrs).
__global__ __launch_bounds__(256)
void gemm_pd_kernel(const unsigned short* __restrict__ fb,
                    const float* __restrict__ sq,
                    __half* __restrict__ pdh, int b, int d) {
  __shared__ unsigned short smA[BM * BK];
  __shared__ unsigned short smB[BN * BK];
  const int t = threadIdx.x;
  const int lane = t & 63;
  const int wave = t >> 6;
  const int wr = wave >> 1, wc = wave & 1;
  const int rowBase = blockIdx.y * BM;
  const int colBase = blockIdx.x * BN;
  const int l15 = lane & 15, l4 = lane >> 4;

  f32x4 acc[4][4] = {};

  for (int kt = 0; kt < d; kt += BK) {
#pragma unroll
    for (int it = 0; it < 4; ++it) {
      const int c = it * 256 + t;      // 1024 16B-chunks per 128x64 tile
      const int r = c >> 3;
      const int kk = (c & 7) * 8;
      gload_lds16(fb + (size_t)(rowBase + r) * d + kt + kk, (char*)smA + c * 16);
      gload_lds16(fb + (size_t)(colBase + r) * d + kt + kk, (char*)smB + c * 16);
    }
    __syncthreads();
#pragma unroll
    for (int ks = 0; ks < 2; ++ks) {
      short8 af[4], bfr[4];
#pragma unroll
      for (int m = 0; m < 4; ++m)
        af[m] = *(const short8*)&smA[(wr * 64 + m * 16 + l15) * BK + ks * 32 + l4 * 8];
#pragma unroll
      for (int nn = 0; nn < 4; ++nn)
        bfr[nn] = *(const short8*)&smB[(wc * 64 + nn * 16 + l15) * BK + ks * 32 + l4 * 8];
#pragma unroll
      for (int m = 0; m < 4; ++m)
#pragma unroll
        for (int nn = 0; nn < 4; ++nn)
          acc[m][nn] = __builtin_amdgcn_mfma_f32_16x16x32_bf16(af[m], bfr[nn], acc[m][nn], 0, 0, 0);
    }
    __syncthreads();
  }

#pragma unroll
  for (int m = 0; m < 4; ++m) {
    const int gr0 = rowBase + wr * 64 + m * 16 + l4 * 4;   // 4 consecutive rows
    const float sq0 = sq[gr0], sq1 = sq[gr0 + 1], sq2 = sq[gr0 + 2], sq3 = sq[gr0 + 3];
#pragma unroll
    for (int nn = 0; nn < 4; ++nn) {
      const int gc = colBase + wc * 64 + nn * 16 + l15;
      const float sqc = sq[gc];
      u16x4 hv;
      {
        float d2 = fmaxf(sq0 + sqc - 2.0f * acc[m][nn][0], 0.0f);
        hv[0] = (gr0 == gc) ? (unsigned short)0x7C00 : f2h_bits(d2);
      }
      {
        float d2 = fmaxf(sq1 + sqc - 2.0f * acc[m][nn][1], 0.0f);
        hv[1] = (gr0 + 1 == gc) ? (unsigned short)0x7C00 : f2h_bits(d2);
      }
      {
        float d2 = fmaxf(sq2 + sqc - 2.0f * acc[m][nn][2], 0.0f);
        hv[2] = (gr0 + 2 == gc) ? (unsigned short)0x7C00 : f2h_bits(d2);
      }
      {
        float d2 = fmaxf(sq3 + sqc - 2.0f * acc[m][nn][3], 0.0f);
        hv[3] = (gr0 + 3 == gc) ? (unsigned short)0x7C00 : f2h_bits(d2);
      }
      // transposed store: row gc, cols gr0..gr0+3 (d^2 symmetric => valid)
      *(u16x4*)&pdh[(size_t)gc * b + gr0] = hv;
    }
  }
}

// ---------- kernel 3: wave-per-row top-16 select (shuffle-only), exact re-rank, loss ----------
// Requires b == 4096 (8 chunks x 64 lanes x 8), d == 512, C == 128.
__global__ __launch_bounds__(256)
void topk_loss_kernel(const __half* __restrict__ pdh,
                      const float* __restrict__ zi, const float* __restrict__ zj,
                      const float* __restrict__ pi, const float* __restrict__ pj,
                      const int* __restrict__ labels,
                      const float* __restrict__ sq,
                      float* __restrict__ rowsum,
                      int n, int d, int C, int b) {
  const int t = threadIdx.x, lane = t & 63, wave = t >> 6;
  const int row = blockIdx.x * 4 + wave;

  // ---- Phase A: load row of packed (fp16 d2, idx); top-16 by repeated wave argmin ----
  const ushort8* rowp = (const ushort8*)(pdh + (size_t)row * b);
  unsigned vv[8][8];
  unsigned cmin[8];
#pragma unroll
  for (int ch = 0; ch < 8; ++ch) {
    ushort8 h = rowp[ch * 64 + lane];
    unsigned mn = 0xFFFFFFFFu;
#pragma unroll
    for (int j = 0; j < 8; ++j) {
      unsigned pk = ((unsigned)h[j] << 16) | (unsigned)(ch * 512 + lane * 8 + j);
      vv[ch][j] = pk;
      mn = min(mn, pk);
    }
    cmin[ch] = mn;
  }

  int c[NC];
#pragma unroll
  for (int r = 0; r < NC; ++r) {
    unsigned best = cmin[0];
#pragma unroll
    for (int ch = 1; ch < 8; ++ch) best = min(best, cmin[ch]);
#pragma unroll
    for (int o = 32; o; o >>= 1) {
      unsigned q = __shfl_xor(best, o, 64);
      best = min(best, q);
    }
    const int idx = (int)(best & 0xFFFFu);
    c[r] = idx;
    if (((idx >> 3) & 63) == lane) {       // owner invalidates + rebuilds its chunk-min
      const int ch = idx >> 9, jj = idx & 7;
#pragma unroll
      for (int cc = 0; cc < 8; ++cc) {
        if (cc == ch) {
          unsigned mn = 0xFFFFFFFFu;
#pragma unroll
          for (int j = 0; j < 8; ++j) {
            if (j == jj) vv[cc][j] = 0xFFFFFFFFu;
            mn = min(mn, vv[cc][j]);
          }
          cmin[cc] = mn;
        }
      }
    }
  }

  // ---- Phase B: exact fp32 d2 for the 16 candidates, batched 4-at-a-time so the
  //      data-dependent global loads overlap instead of serializing ----
  const float* fme = (row < n) ? (zi + (size_t)row * d) : (zj + (size_t)(row - n) * d);
  float fr[8];
#pragma unroll
  for (int q = 0; q < 8; ++q) fr[q] = fme[lane + 64 * q];
  const float sqr = sq[row];

  float p[NC];
#pragma unroll
  for (int g = 0; g < 4; ++g) {
    float gv0[8], gv1[8], gv2[8], gv3[8];
    const int j0 = c[g * 4 + 0], j1 = c[g * 4 + 1], j2 = c[g * 4 + 2], j3 = c[g * 4 + 3];
    const float* gp0 = (j0 < n) ? (zi + (size_t)j0 * d) : (zj + (size_t)(j0 - n) * d);
    const float* gp1 = (j1 < n) ? (zi + (size_t)j1 * d) : (zj + (size_t)(j1 - n) * d);
    const float* gp2 = (j2 < n) ? (zi + (size_t)j2 * d) : (zj + (size_t)(j2 - n) * d);
    const float* gp3 = (j3 < n) ? (zi + (size_t)j3 * d) : (zj + (size_t)(j3 - n) * d);
#pragma unroll
    for (int q = 0; q < 8; ++q) gv0[q] = gp0[lane + 64 * q];
#pragma unroll
    for (int q = 0; q < 8; ++q) gv1[q] = gp1[lane + 64 * q];
#pragma unroll
    for (int q = 0; q < 8; ++q) gv2[q] = gp2[lane + 64 * q];
#pragma unroll
    for (int q = 0; q < 8; ++q) gv3[q] = gp3[lane + 64 * q];

    float pt0 = 0.f, pt1 = 0.f, pt2 = 0.f, pt3 = 0.f;
#pragma unroll
    for (int q = 0; q < 8; ++q) {
      pt0 += fr[q] * gv0[q];
      pt1 += fr[q] * gv1[q];
      pt2 += fr[q] * gv2[q];
      pt3 += fr[q] * gv3[q];
    }
#pragma unroll
    for (int o = 32; o; o >>= 1) {
      pt0 += __shfl_xor(pt0, o, 64);
      pt1 += __shfl_xor(pt1, o, 64);
      pt2 += __shfl_xor(pt2, o, 64);
      pt3 += __shfl_xor(pt3, o, 64);
    }
    p[g * 4 + 0] = sqrtf(fmaxf(sqr + sq[j0] - 2.0f * pt0, 0.0f));
    p[g * 4 + 1] = sqrtf(fmaxf(sqr + sq[j1] - 2.0f * pt1, 0.0f));
    p[g * 4 + 2] = sqrtf(fmaxf(sqr + sq[j2] - 2.0f * pt2, 0.0f));
    p[g * 4 + 3] = sqrtf(fmaxf(sqr + sq[j3] - 2.0f * pt3, 0.0f));
  }

  // ---- Phase C: radius + branchless pairwise ranks (all compile-time indices) ----
  float r0 = p[0];
#pragma unroll
  for (int k = 1; k < NC; ++k) r0 = fminf(r0, p[k]);

  int rank[NC];
#pragma unroll
  for (int k = 0; k < NC; ++k) rank[k] = 0;
#pragma unroll
  for (int k = 1; k < NC; ++k) {
#pragma unroll
    for (int j = 0; j < k; ++j) {
      const bool tt = p[j] <= p[k];   // tie -> earlier extraction wins (lower approx (d2,idx))
      rank[k] += tt ? 1 : 0;
      rank[j] += tt ? 0 : 1;
    }
  }

  // ---- Phase D: masked contributions; prob dot only when mask passes (wave-uniform) ----
  const int ri = (row < n) ? row : row - n;
  const int li = labels[ri];
  const float* pme = (row < n) ? (pi + (size_t)row * C) : (pj + (size_t)(row - n) * C);
  const float pr0 = pme[lane], pr1 = pme[lane + 64];

  float tot = 0.f;
#pragma unroll
  for (int k = 0; k < NC; ++k) {
    const int j = c[k];
    const int rj = (j < n) ? j : j - n;
    const int lj = labels[rj];
    const bool m = (rank[k] < 10) & (li != -1) & (lj != -1) & (li == lj) & (ri != rj);
    if (m) {   // identical across lanes -> uniform branch
      const float* q = (j < n) ? (pi + (size_t)j * C) : (pj + (size_t)(j - n) * C);
      float part = pr0 * q[lane] + pr1 * q[lane + 64];
#pragma unroll
      for (int o = 32; o; o >>= 1) part += __shfl_xor(part, o, 64);
      const float w = 1.0f - fminf(fmaxf((p[k] - r0) / r0, 0.0f), 1.0f);
      tot += w * part;
    }
  }
  if (lane == 0) rowsum[row] = tot;
}

// ---------- kernel 4: deterministic final reduce ----------
__global__ __launch_bounds__(256)
void final_reduce_kernel(const float* __restrict__ rowsum, float* __restrict__ out, int b) {
  __shared__ float wredf[4];
  const int t = threadIdx.x, lane = t & 63, wave = t >> 6;
  float s = 0.f;
  for (int c = t; c < b; c += 256) s += rowsum[c];
#pragma unroll
  for (int o = 32; o; o >>= 1) s += __shfl_xor(s, o, 64);
  if (lane == 0) wredf[wave] = s;
  __syncthreads();
  if (t == 0) {
    float tot = ((wredf[0] + wredf[1]) + wredf[2]) + wredf[3];
    out[0] = tot / ((float)b * (float)b);
  }
}

extern "C" void kernel_launch(void* const* d_in, const int* in_sizes, int n_in,
                              void* d_out, int out_size, void* d_ws, size_t ws_size,
                              hipStream_t stream) {
  const float* zi = (const float*)d_in[0];
  const float* zj = (const float*)d_in[1];
  const float* pi = (const float*)d_in[2];
  const float* pj = (const float*)d_in[3];
  const int* labels = (const int*)d_in[4];

  const int n = in_sizes[4];          // 2048
  const int d = in_sizes[0] / n;      // 512
  const int C = in_sizes[2] / n;      // 128
  const int b = 2 * n;                // 4096

  char* ws = (char*)d_ws;
  size_t off = 0;
  unsigned short* fb = (unsigned short*)(ws + off);
  off += ((size_t)b * d * 2 + 255) & ~(size_t)255;
  float* sq = (float*)(ws + off);
  off += ((size_t)b * 4 + 255) & ~(size_t)255;
  float* rowsum = (float*)(ws + off);
  off += ((size_t)b * 4 + 255) & ~(size_t)255;
  __half* pdh = (__half*)(ws + off);
  off += (size_t)b * b * 2;
  if (ws_size < off) return;  // workspace too small — bail rather than corrupt

  prep_kernel<<<b, 256, 0, stream>>>(zi, zj, fb, sq, n, d);
  dim3 grid(b / BN, b / BM);
  gemm_pd_kernel<<<grid, 256, 0, stream>>>(fb, sq, pdh, b, d);
  topk_loss_kernel<<<b / 4, 256, 0, stream>>>(pdh, zi, zj, pi, pj, labels, sq, rowsum, n, d, C, b);
  final_reduce_kernel<<<1, 256, 0, stream>>>(rowsum, (float*)d_out, b);
}